// Round 10
// baseline (74.859 us; speedup 1.0000x reference)
//
#include <hip/hip_runtime.h>
#include <math.h>

#ifndef M_PI
#define M_PI 3.14159265358979323846
#endif

#define NSIDE  128
#define NTHETA 511            // = LMAX = number of rings
#define MMAX   257
#define NPIX   196608
#define KSPLIT 4              // equal k-chunks per m (load balance granularity)

// Kernel 1: ftm[k][m] = sum_l x[l][m] * pct[m][l][k], computed ONLY for
// k in [klo(m), 510-klo(m)] where klo = ceil(m/2)-1  (ring k consumes
// harmonic m iff nphi(k) >= 2m). EXACTLY the round-6 structure (best so
// far, 63.6 us) with ONE change: pct loads are NON-TEMPORAL, so the
// 268 MB one-pass stream does not allocate/thrash the 256 MB L3.
__global__ __launch_bounds__(128)
void ftm_kernel(const float* __restrict__ x_re,
                const float* __restrict__ x_im,
                const float* __restrict__ pct,
                float* __restrict__ ftm_re,
                float* __restrict__ ftm_im)
{
    const int m  = blockIdx.x >> 2;          // 0..256
    const int j  = blockIdx.x & 3;
    const int klo = (m >= 2) ? ((m + 1) / 2 - 1) : 0;
    const int cnt = NTHETA - 2 * klo;        // valid columns (257..511)
    const int lo  = klo + (cnt * j) / KSPLIT;
    const int hi  = klo + (cnt * (j + 1)) / KSPLIT;   // chunk <= 128 cols

    __shared__ float xr[NTHETA];
    __shared__ float xi[NTHETA];
    const int tid = threadIdx.x;
    for (int i = tid; i < NTHETA; i += 128) {
        xr[i] = x_re[(size_t)i * MMAX + m];
        xi[i] = x_im[(size_t)i * MMAX + m];
    }
    __syncthreads();

    const int k = lo + tid;
    if (k >= hi) return;

    const float* p = pct + (size_t)m * NTHETA * NTHETA + k;
    float ar = 0.f, ai = 0.f;

    int l = 0;
    for (; l <= NTHETA - 8; l += 8) {
        float v[8];
        #pragma unroll
        for (int u = 0; u < 8; ++u)
            v[u] = __builtin_nontemporal_load(p + (size_t)(l + u) * NTHETA);
        #pragma unroll
        for (int u = 0; u < 8; ++u) {
            ar = fmaf(xr[l + u], v[u], ar);
            ai = fmaf(xi[l + u], v[u], ai);
        }
    }
    {   // batched tail: rows 504..510 (7 loads issued together)
        float v[7];
        #pragma unroll
        for (int u = 0; u < 7; ++u)
            v[u] = __builtin_nontemporal_load(p + (size_t)(504 + u) * NTHETA);
        #pragma unroll
        for (int u = 0; u < 7; ++u) {
            ar = fmaf(xr[504 + u], v[u], ar);
            ai = fmaf(xi[504 + u], v[u], ai);
        }
    }

    ftm_re[(size_t)k * MMAX + m] = ar;
    ftm_im[(size_t)k * MMAX + m] = ai;
}

// Kernel 2: direct inverse rFFT per ring at pixel azimuths (unchanged R6).
// f[cum+k] = fr[0] + 2*sum_{m=1}^{N/2-1} (fr[m]*cos(m*phi) - fi[m]*sin(m*phi))
//                  +     (fr[N/2]*cos(..) - fi[N/2]*sin(..))
// with phi = phi0(t) + 2*pi*k/nphi. Reads fr/fi only for m <= nphi/2 --
// exactly the slots ftm_kernel writes.
__global__ __launch_bounds__(256)
void ring_kernel(const float* __restrict__ ftm_re,
                 const float* __restrict__ ftm_im,
                 float* __restrict__ out)
{
    const int t = blockIdx.y;
    int nphi, cum;
    double phi0;
    if (t < NSIDE - 1) {                       // north polar cap
        nphi = 4 * (t + 1);
        cum  = 2 * t * (t + 1);
        phi0 = M_PI / (4.0 * (t + 1));
    } else if (t <= 3 * NSIDE - 1) {           // equatorial belt
        nphi = 4 * NSIDE;
        cum  = 2 * (NSIDE - 1) * NSIDE + (t - (NSIDE - 1)) * 4 * NSIDE;
        phi0 = (M_PI / (2.0 * NSIDE)) * (0.5 * (double)((t - NSIDE + 2) % 2));
    } else {                                   // south polar cap
        int s = 4 * NSIDE - 1 - t;
        nphi = 4 * s;
        cum  = NPIX - 2 * s * (s + 1);
        phi0 = M_PI / (4.0 * s);
    }
    if ((int)blockIdx.x * 256 >= nphi) return;  // block-uniform early exit

    const int mtop = nphi / 2;                  // inclusive top harmonic (<= 256)
    __shared__ float fr[MMAX];
    __shared__ float fi[MMAX];
    for (int i = threadIdx.x; i <= mtop; i += 256) {
        fr[i] = ftm_re[(size_t)t * MMAX + i];
        fi[i] = ftm_im[(size_t)t * MMAX + i];
    }
    __syncthreads();

    const int k = blockIdx.x * 256 + threadIdx.x;
    if (k >= nphi) return;

    double phi = phi0 + (2.0 * M_PI) * ((double)k / (double)nphi);
    float sp, cp;
    sincosf((float)phi, &sp, &cp);

    float cr = 1.f, ci = 0.f;                   // e^{i*m*phi}, m=0
    float acc = fr[0];
    for (int m = 1; m < mtop; ++m) {
        float nr = cr * cp - ci * sp;
        float ni = cr * sp + ci * cp;
        cr = nr; ci = ni;
        acc += 2.f * (fr[m] * cr - fi[m] * ci);
    }
    {   // m = mtop, weight 1
        float nr = cr * cp - ci * sp;
        float ni = cr * sp + ci * cp;
        acc += fr[mtop] * nr - fi[mtop] * ni;
    }
    out[cum + k] = acc;
}

extern "C" void kernel_launch(void* const* d_in, const int* in_sizes, int n_in,
                              void* d_out, int out_size, void* d_ws, size_t ws_size,
                              hipStream_t stream)
{
    const float* x_re = (const float*)d_in[0];
    const float* x_im = (const float*)d_in[1];
    const float* pct  = (const float*)d_in[2];
    float* out = (float*)d_out;

    float* ftm_re = (float*)d_ws;                       // NTHETA*MMAX floats
    float* ftm_im = ftm_re + (size_t)NTHETA * MMAX;     // NTHETA*MMAX floats

    ftm_kernel<<<dim3(MMAX * KSPLIT), 128, 0, stream>>>(x_re, x_im, pct, ftm_re, ftm_im);
    ring_kernel<<<dim3(2, NTHETA), 256, 0, stream>>>(ftm_re, ftm_im, out);
}

// Round 11
// 64.258 us; speedup vs baseline: 1.1650x; 1.1650x over previous
//
#include <hip/hip_runtime.h>
#include <math.h>

#ifndef M_PI
#define M_PI 3.14159265358979323846
#endif

#define NSIDE  128
#define NTHETA 511            // = LMAX = number of rings
#define MMAX   257
#define NPIX   196608
#define KSPLIT 4              // equal k-chunks per m (load balance granularity)

// Kernel 1: ftm[k][m] = sum_l x[l][m] * pct[m][l][k], computed ONLY for
// k in [klo(m), 510-klo(m)] where klo = ceil(m/2)-1  (ring k consumes
// harmonic m iff nphi(k) >= 2m). EXACTLY the round-6 structure (best,
// 63.6 us) with ONE change: block -> (m, j) mapping pairs m=q with
// m=256-q in adjacent block IDs. cnt(q)+cnt(256-q) = 768 = const, so
// every contiguous dispatch stripe carries equal bytes -> no heavy-block
// straggler tail at the 4-blocks/CU quantization.
__global__ __launch_bounds__(128)
void ftm_kernel(const float* __restrict__ x_re,
                const float* __restrict__ x_im,
                const float* __restrict__ pct,
                float* __restrict__ ftm_re,
                float* __restrict__ ftm_im)
{
    const int q    = blockIdx.x >> 3;        // 0..128
    const int r    = blockIdx.x & 7;
    const int side = r & 1;
    const int j    = r >> 1;                 // 0..3
    if (q == 128 && side) return;            // m=128 covered once
    const int m = side ? 256 - q : q;

    const int klo = (m >= 2) ? ((m + 1) / 2 - 1) : 0;
    const int cnt = NTHETA - 2 * klo;        // valid columns (257..511)
    const int lo  = klo + (cnt * j) / KSPLIT;
    const int hi  = klo + (cnt * (j + 1)) / KSPLIT;   // chunk <= 128 cols

    __shared__ float xr[NTHETA];
    __shared__ float xi[NTHETA];
    const int tid = threadIdx.x;
    for (int i = tid; i < NTHETA; i += 128) {
        xr[i] = x_re[(size_t)i * MMAX + m];
        xi[i] = x_im[(size_t)i * MMAX + m];
    }
    __syncthreads();

    const int k = lo + tid;
    if (k >= hi) return;

    const float* p = pct + (size_t)m * NTHETA * NTHETA + k;
    float ar = 0.f, ai = 0.f;

    int l = 0;
    for (; l <= NTHETA - 8; l += 8) {
        float v[8];
        #pragma unroll
        for (int u = 0; u < 8; ++u) v[u] = p[(size_t)(l + u) * NTHETA];
        #pragma unroll
        for (int u = 0; u < 8; ++u) {
            ar = fmaf(xr[l + u], v[u], ar);
            ai = fmaf(xi[l + u], v[u], ai);
        }
    }
    {   // batched tail: rows 504..510 (7 loads issued together)
        float v[7];
        #pragma unroll
        for (int u = 0; u < 7; ++u) v[u] = p[(size_t)(504 + u) * NTHETA];
        #pragma unroll
        for (int u = 0; u < 7; ++u) {
            ar = fmaf(xr[504 + u], v[u], ar);
            ai = fmaf(xi[504 + u], v[u], ai);
        }
    }

    ftm_re[(size_t)k * MMAX + m] = ar;
    ftm_im[(size_t)k * MMAX + m] = ai;
}

// Kernel 2: direct inverse rFFT per ring at pixel azimuths (unchanged R6).
// f[cum+k] = fr[0] + 2*sum_{m=1}^{N/2-1} (fr[m]*cos(m*phi) - fi[m]*sin(m*phi))
//                  +     (fr[N/2]*cos(..) - fi[N/2]*sin(..))
// with phi = phi0(t) + 2*pi*k/nphi. Reads fr/fi only for m <= nphi/2 --
// exactly the slots ftm_kernel writes.
__global__ __launch_bounds__(256)
void ring_kernel(const float* __restrict__ ftm_re,
                 const float* __restrict__ ftm_im,
                 float* __restrict__ out)
{
    const int t = blockIdx.y;
    int nphi, cum;
    double phi0;
    if (t < NSIDE - 1) {                       // north polar cap
        nphi = 4 * (t + 1);
        cum  = 2 * t * (t + 1);
        phi0 = M_PI / (4.0 * (t + 1));
    } else if (t <= 3 * NSIDE - 1) {           // equatorial belt
        nphi = 4 * NSIDE;
        cum  = 2 * (NSIDE - 1) * NSIDE + (t - (NSIDE - 1)) * 4 * NSIDE;
        phi0 = (M_PI / (2.0 * NSIDE)) * (0.5 * (double)((t - NSIDE + 2) % 2));
    } else {                                   // south polar cap
        int s = 4 * NSIDE - 1 - t;
        nphi = 4 * s;
        cum  = NPIX - 2 * s * (s + 1);
        phi0 = M_PI / (4.0 * s);
    }
    if ((int)blockIdx.x * 256 >= nphi) return;  // block-uniform early exit

    const int mtop = nphi / 2;                  // inclusive top harmonic (<= 256)
    __shared__ float fr[MMAX];
    __shared__ float fi[MMAX];
    for (int i = threadIdx.x; i <= mtop; i += 256) {
        fr[i] = ftm_re[(size_t)t * MMAX + i];
        fi[i] = ftm_im[(size_t)t * MMAX + i];
    }
    __syncthreads();

    const int k = blockIdx.x * 256 + threadIdx.x;
    if (k >= nphi) return;

    double phi = phi0 + (2.0 * M_PI) * ((double)k / (double)nphi);
    float sp, cp;
    sincosf((float)phi, &sp, &cp);

    float cr = 1.f, ci = 0.f;                   // e^{i*m*phi}, m=0
    float acc = fr[0];
    for (int m = 1; m < mtop; ++m) {
        float nr = cr * cp - ci * sp;
        float ni = cr * sp + ci * cp;
        cr = nr; ci = ni;
        acc += 2.f * (fr[m] * cr - fi[m] * ci);
    }
    {   // m = mtop, weight 1
        float nr = cr * cp - ci * sp;
        float ni = cr * sp + ci * cp;
        acc += fr[mtop] * nr - fi[mtop] * ni;
    }
    out[cum + k] = acc;
}

extern "C" void kernel_launch(void* const* d_in, const int* in_sizes, int n_in,
                              void* d_out, int out_size, void* d_ws, size_t ws_size,
                              hipStream_t stream)
{
    const float* x_re = (const float*)d_in[0];
    const float* x_im = (const float*)d_in[1];
    const float* pct  = (const float*)d_in[2];
    float* out = (float*)d_out;

    float* ftm_re = (float*)d_ws;                       // NTHETA*MMAX floats
    float* ftm_im = ftm_re + (size_t)NTHETA * MMAX;     // NTHETA*MMAX floats

    ftm_kernel<<<dim3(129 * 8), 128, 0, stream>>>(x_re, x_im, pct, ftm_re, ftm_im);
    ring_kernel<<<dim3(2, NTHETA), 256, 0, stream>>>(ftm_re, ftm_im, out);
}

// Round 12
// 63.570 us; speedup vs baseline: 1.1776x; 1.0108x over previous
//
#include <hip/hip_runtime.h>
#include <math.h>

#ifndef M_PI
#define M_PI 3.14159265358979323846
#endif

#define NSIDE  128
#define NTHETA 511            // = LMAX = number of rings
#define MMAX   257
#define NPIX   196608
#define KSPLIT 4              // equal k-chunks per m (load balance granularity)

// Kernel 1: ftm[k][m] = sum_l x[l][m] * pct[m][l][k], computed ONLY for
// k in [klo(m), 510-klo(m)] where klo = ceil(m/2)-1  (ring k consumes
// harmonic m iff nphi(k) >= 2m). Cuts pct traffic 268 MB -> 202 MB.
// Block = (m, j): j-th of 4 equal chunks of the valid k-range.
// This is the best-measured configuration (round 6, 63.6 us): 10 rounds of
// alternatives (deeper unroll, TLP, contiguous float4, NT loads, pair
// balancing, transpose staging, LDS pipelines) were all neutral or worse --
// the pct read stream is pinned at ~4.4-4.5 TB/s in every structure.
__global__ __launch_bounds__(128)
void ftm_kernel(const float* __restrict__ x_re,
                const float* __restrict__ x_im,
                const float* __restrict__ pct,
                float* __restrict__ ftm_re,
                float* __restrict__ ftm_im)
{
    const int m  = blockIdx.x >> 2;          // 0..256
    const int j  = blockIdx.x & 3;
    const int klo = (m >= 2) ? ((m + 1) / 2 - 1) : 0;
    const int cnt = NTHETA - 2 * klo;        // valid columns (257..511)
    const int lo  = klo + (cnt * j) / KSPLIT;
    const int hi  = klo + (cnt * (j + 1)) / KSPLIT;   // chunk <= 128 cols

    __shared__ float xr[NTHETA];
    __shared__ float xi[NTHETA];
    const int tid = threadIdx.x;
    for (int i = tid; i < NTHETA; i += 128) {
        xr[i] = x_re[(size_t)i * MMAX + m];
        xi[i] = x_im[(size_t)i * MMAX + m];
    }
    __syncthreads();

    const int k = lo + tid;
    if (k >= hi) return;

    const float* p = pct + (size_t)m * NTHETA * NTHETA + k;
    float ar = 0.f, ai = 0.f;

    int l = 0;
    for (; l <= NTHETA - 8; l += 8) {
        float v[8];
        #pragma unroll
        for (int u = 0; u < 8; ++u) v[u] = p[(size_t)(l + u) * NTHETA];
        #pragma unroll
        for (int u = 0; u < 8; ++u) {
            ar = fmaf(xr[l + u], v[u], ar);
            ai = fmaf(xi[l + u], v[u], ai);
        }
    }
    {   // batched tail: rows 504..510 (7 loads issued together)
        float v[7];
        #pragma unroll
        for (int u = 0; u < 7; ++u) v[u] = p[(size_t)(504 + u) * NTHETA];
        #pragma unroll
        for (int u = 0; u < 7; ++u) {
            ar = fmaf(xr[504 + u], v[u], ar);
            ai = fmaf(xi[504 + u], v[u], ai);
        }
    }

    ftm_re[(size_t)k * MMAX + m] = ar;
    ftm_im[(size_t)k * MMAX + m] = ai;
}

// Kernel 2: direct inverse rFFT per ring at pixel azimuths.
// f[cum+k] = fr[0] + 2*sum_{m=1}^{N/2-1} (fr[m]*cos(m*phi) - fi[m]*sin(m*phi))
//                  +     (fr[N/2]*cos(..) - fi[N/2]*sin(..))
// with phi = phi0(t) + 2*pi*k/nphi. Reads fr/fi only for m <= nphi/2 --
// exactly the slots ftm_kernel writes.
__global__ __launch_bounds__(256)
void ring_kernel(const float* __restrict__ ftm_re,
                 const float* __restrict__ ftm_im,
                 float* __restrict__ out)
{
    const int t = blockIdx.y;
    int nphi, cum;
    double phi0;
    if (t < NSIDE - 1) {                       // north polar cap
        nphi = 4 * (t + 1);
        cum  = 2 * t * (t + 1);
        phi0 = M_PI / (4.0 * (t + 1));
    } else if (t <= 3 * NSIDE - 1) {           // equatorial belt
        nphi = 4 * NSIDE;
        cum  = 2 * (NSIDE - 1) * NSIDE + (t - (NSIDE - 1)) * 4 * NSIDE;
        phi0 = (M_PI / (2.0 * NSIDE)) * (0.5 * (double)((t - NSIDE + 2) % 2));
    } else {                                   // south polar cap
        int s = 4 * NSIDE - 1 - t;
        nphi = 4 * s;
        cum  = NPIX - 2 * s * (s + 1);
        phi0 = M_PI / (4.0 * s);
    }
    if ((int)blockIdx.x * 256 >= nphi) return;  // block-uniform early exit

    const int mtop = nphi / 2;                  // inclusive top harmonic (<= 256)
    __shared__ float fr[MMAX];
    __shared__ float fi[MMAX];
    for (int i = threadIdx.x; i <= mtop; i += 256) {
        fr[i] = ftm_re[(size_t)t * MMAX + i];
        fi[i] = ftm_im[(size_t)t * MMAX + i];
    }
    __syncthreads();

    const int k = blockIdx.x * 256 + threadIdx.x;
    if (k >= nphi) return;

    double phi = phi0 + (2.0 * M_PI) * ((double)k / (double)nphi);
    float sp, cp;
    sincosf((float)phi, &sp, &cp);

    float cr = 1.f, ci = 0.f;                   // e^{i*m*phi}, m=0
    float acc = fr[0];
    for (int m = 1; m < mtop; ++m) {
        float nr = cr * cp - ci * sp;
        float ni = cr * sp + ci * cp;
        cr = nr; ci = ni;
        acc += 2.f * (fr[m] * cr - fi[m] * ci);
    }
    {   // m = mtop, weight 1
        float nr = cr * cp - ci * sp;
        float ni = cr * sp + ci * cp;
        acc += fr[mtop] * nr - fi[mtop] * ni;
    }
    out[cum + k] = acc;
}

extern "C" void kernel_launch(void* const* d_in, const int* in_sizes, int n_in,
                              void* d_out, int out_size, void* d_ws, size_t ws_size,
                              hipStream_t stream)
{
    const float* x_re = (const float*)d_in[0];
    const float* x_im = (const float*)d_in[1];
    const float* pct  = (const float*)d_in[2];
    float* out = (float*)d_out;

    float* ftm_re = (float*)d_ws;                       // NTHETA*MMAX floats
    float* ftm_im = ftm_re + (size_t)NTHETA * MMAX;     // NTHETA*MMAX floats

    ftm_kernel<<<dim3(MMAX * KSPLIT), 128, 0, stream>>>(x_re, x_im, pct, ftm_re, ftm_im);
    ring_kernel<<<dim3(2, NTHETA), 256, 0, stream>>>(ftm_re, ftm_im, out);
}